// Round 3
// baseline (161.612 us; speedup 1.0000x reference)
//
#include <hip/hip_runtime.h>

#define N_NODES 100000
#define N_EDGES 1000000
#define D 64

#define NFINE 782             // fine bin = dst >> 7 (128 nodes each)
#define CAP2 1536             // per-bin cap: mean 1280 + ~7 sigma
#define CHUNK 4096            // edges per build block
#define BUILD_BLOCKS 245      // ceil(1e6 / 4096)
#define CONV_THREADS 1600000  // N*D/4 float4s
#define CONV_BLOCKS_F 1563    // ceil(1.6e6 / 1024)
#define FUSED_BLOCKS (BUILD_BLOCKS + CONV_BLOCKS_F)
#define CONS_BLOCKS 1564      // 782 bins x 2 halves, 64 nodes / 512-thr block
#define STR 132               // As/Bs row stride in u16
#define SCAP 1024             // sorted_s slots per 64-node half
#define CSTR 16               // cur2 stride in ints: one counter per 64B line

typedef unsigned short u16;
typedef unsigned int u32;
typedef unsigned char u8;
using bf16x8 = __attribute__((ext_vector_type(8))) short;
using f32x4  = __attribute__((ext_vector_type(4))) float;

__device__ __forceinline__ u16 f2bf(float f) {   // RNE float->bf16
    u32 u = __float_as_uint(f);
    return (u16)((u + 0x7FFF + ((u >> 16) & 1)) >> 16);
}
__device__ __forceinline__ float bf2f(u16 v) {
    return __uint_as_float(((u32)v) << 16);
}

// ===========================================================================
// conv_build: fused. Blocks [0,245): LDS counting sort of edges into 782
// fine 128-node dst-bins (cur2 stride CSTR: one counter per 64B line to
// de-serialize the ~190K global reservation atomics). Blocks [245,1808):
// x fp32 -> xb bf16 (1 float4/thread). Build blocks dispatched first so
// their latency overlaps conv's streaming. cur2 zeroed by hipMemsetAsync.
// Packed pair = src(17b) | dst_local7 << 17.
// ===========================================================================
__global__ __launch_bounds__(1024) void conv_build_kernel(
    const float* __restrict__ x, u16* __restrict__ xb,
    const int* __restrict__ ei, int* __restrict__ cur2,
    u32* __restrict__ pairs2) {
    __shared__ u32 sorted[CHUNK];    // 16 KB
    __shared__ u16 binof[CHUNK];     //  8 KB
    __shared__ int hist[NFINE];
    __shared__ int off_l[NFINE];
    __shared__ int cur_l[NFINE];
    __shared__ int base_g[NFINE];
    __shared__ int wsum[16];

    if (blockIdx.x >= BUILD_BLOCKS) {
        // ---- conv path ----
        int i = (blockIdx.x - BUILD_BLOCKS) * 1024 + threadIdx.x;
        if (i < CONV_THREADS) {
            float4 v = ((const float4*)x)[i];
            ((ushort4*)xb)[i] =
                make_ushort4(f2bf(v.x), f2bf(v.y), f2bf(v.z), f2bf(v.w));
        }
        return;
    }

    // ---- build path ----
    int b = blockIdx.x;
    int t = threadIdx.x;
    int ln = t & 63;
    int wv = t >> 6;

    // int64/int32 detect: indices < 2^17 -> int64 odd u32 words all zero
    const u32* uu = (const u32*)ei;
    int f = 1;
    #pragma unroll
    for (int i = 1; i < 16; i += 2)
        if (uu[i] != 0u) f = 0;

    if (t < NFINE) hist[t] = 0;
    __syncthreads();

    int e0 = b * CHUNK;
    int e1 = min(e0 + CHUNK, N_EDGES);
    int ne = e1 - e0;

    // load edges to registers (coalesced uint2 for int64 path) + histogram
    const uint2* e64 = (const uint2*)ei;
    int srcv[4], dstv[4];
    #pragma unroll
    for (int i = 0; i < 4; i++) {
        int ee = e0 + t + i * 1024;
        bool ok = ee < e1;
        if (f) {
            uint2 sv = ok ? e64[ee] : make_uint2(0u, 0u);
            uint2 dv = ok ? e64[N_EDGES + ee] : make_uint2(0u, 0u);
            srcv[i] = (int)sv.x;
            dstv[i] = ok ? (int)dv.x : -1;
        } else {
            srcv[i] = ok ? ei[ee] : 0;
            dstv[i] = ok ? ei[N_EDGES + ee] : -1;
        }
    }
    #pragma unroll
    for (int i = 0; i < 4; i++)
        if (dstv[i] >= 0) atomicAdd(&hist[dstv[i] >> 7], 1);
    __syncthreads();

    // two-level wave scan over 782 bins
    int h = (t < NFINE) ? hist[t] : 0;
    int inc = h;
    #pragma unroll
    for (int o = 1; o < 64; o <<= 1) {
        int v = __shfl_up(inc, o);
        if (ln >= o) inc += v;
    }
    if (ln == 63) wsum[wv] = inc;
    __syncthreads();
    if (t < 16) {
        int w = wsum[t];
        int winc = w;
        #pragma unroll
        for (int o = 1; o < 16; o <<= 1) {
            int v = __shfl_up(winc, o);
            if (t >= o) winc += v;
        }
        wsum[t] = winc - w;          // exclusive wave offset
    }
    __syncthreads();
    if (t < NFINE) {
        int ex = inc - h + wsum[wv]; // exclusive prefix
        off_l[t] = ex;
        cur_l[t] = ex;
        base_g[t] = h ? atomicAdd(&cur2[t * CSTR], h) : 0;
    }
    __syncthreads();

    // placement: counting-sort into LDS
    #pragma unroll
    for (int i = 0; i < 4; i++) {
        if (dstv[i] >= 0) {
            int fine = dstv[i] >> 7;
            int slot = atomicAdd(&cur_l[fine], 1);
            sorted[slot] = (u32)srcv[i] | ((u32)(dstv[i] & 127) << 17);
            binof[slot] = (u16)fine;
        }
    }
    __syncthreads();

    // linear coalesced flush
    for (int i = t; i < ne; i += 1024) {
        int fine = binof[i];
        int pos = base_g[fine] + (i - off_l[fine]);
        if (pos < CAP2)
            pairs2[(size_t)fine * CAP2 + pos] = sorted[i];
    }
}

// ===========================================================================
// cons5: grid 1564, block 512 (8 waves), 64 nodes per block.
// vs round-2 cons4:
//   - DEGREE-SORTED node->wave assignment: rank each of the 64 nodes by
//     degree (64-step shfl compare, once per block); wave w gathers ranks
//     [8w,8w+8) -> similar degrees -> sum of wave-max iters drops ~25%.
//   - SOFTWARE-PIPELINED gather: two 4-load groups (A,B) in flight;
//     prefetch B, FMA A (vmcnt(4) overlap), prefetch next A, FMA B.
//     Uniform branches skip B-FMA / next-A prefetch past maxd.
//   - self-row load moved after the loop (4 fewer live VGPRs in loop).
// LDS 38.7 KB -> 4 blocks/CU; __launch_bounds__(512,8) pins VGPR <= 64.
// MFMA epilogue unchanged (C/D col=lane&15, row=quad*4+reg; m89/m91).
// ===========================================================================
__global__ __launch_bounds__(512, 8) void cons5_kernel(
    const u16* __restrict__ xb, const float* __restrict__ Wl,
    const float* __restrict__ bl, const float* __restrict__ Wr,
    const int* __restrict__ cur2, const u32* __restrict__ pairs2,
    float* __restrict__ out) {
    __shared__ u16 Bs[64 * STR];     // 16896 B
    __shared__ u16 As[64 * STR];     // 16896 B
    __shared__ int sorted_s[SCAP];   //  4096 B
    __shared__ int deg_l[64];
    __shared__ int off_l[64];
    __shared__ int cur_l[64];
    __shared__ u8  perm_s[64];

    int tid = threadIdx.x;
    int bin = blockIdx.x >> 1;
    int half = blockIdx.x & 1;
    int nbase = bin * 128 + half * 64;
    if (nbase >= N_NODES) return;    // last half-block is all-phantom

    int lane = tid & 63;
    int wv = tid >> 6;

    // ---- issue pair loads first (long-latency, hide under staging) ----
    int cnt = min(cur2[bin * CSTR], CAP2);
    const u32* pb = &pairs2[(size_t)bin * CAP2];
    u32 ve[3];
    #pragma unroll
    for (int i = 0; i < 3; i++) {
        int e = tid + i * 512;
        ve[i] = (e < cnt) ? pb[e] : 0xFFFFFFFFu;   // sentinel fails half test
    }

    if (tid < 64) { deg_l[tid] = 0; cur_l[tid] = 0; }
    if (tid == 0) sorted_s[0] = 0;   // safe slot for d==0 lanes

    // Stage Bs: row o = [Wl[o][0:64] | Wr[o][0:64]] bf16, stride STR
    if (tid < 256) {
        int row = tid >> 2;
        int seg = tid & 3;
        const float4* wlf = (const float4*)Wl;
        const float4* wrf = (const float4*)Wr;
        #pragma unroll
        for (int j = 0; j < 4; j++) {
            float4 a = wlf[row * 16 + seg * 4 + j];
            float4 bq = wrf[row * 16 + seg * 4 + j];
            *(ushort4*)&Bs[row * STR + seg * 16 + j * 4] =
                make_ushort4(f2bf(a.x), f2bf(a.y), f2bf(a.z), f2bf(a.w));
            *(ushort4*)&Bs[row * STR + 64 + seg * 16 + j * 4] =
                make_ushort4(f2bf(bq.x), f2bf(bq.y), f2bf(bq.z), f2bf(bq.w));
        }
    }
    __syncthreads();

    // ---- histogram over this half's 64 local nodes ----
    #pragma unroll
    for (int i = 0; i < 3; i++) {
        u32 v = ve[i];
        if ((int)(v >> 23) == half) atomicAdd(&deg_l[(v >> 17) & 63], 1);
    }
    __syncthreads();

    // ---- scan + degree-rank (single wave) ----
    if (tid < 64) {
        int dd = deg_l[tid];
        int inc = dd;
        #pragma unroll
        for (int o = 1; o < 64; o <<= 1) {
            int v = __shfl_up(inc, o);
            if (lane >= o) inc += v;
        }
        off_l[tid] = inc - dd;
        int rank = 0;
        for (int j = 0; j < 64; j++) {
            int dj = __shfl(dd, j);
            rank += (dj > dd) || (dj == dd && j < tid);
        }
        perm_s[rank] = (u8)tid;      // rank 0 = highest degree
    }
    __syncthreads();

    // ---- counting-sort placement ----
    #pragma unroll
    for (int i = 0; i < 3; i++) {
        u32 v = ve[i];
        if ((int)(v >> 23) == half) {
            int lnn = (v >> 17) & 63;
            int p = off_l[lnn] + atomicAdd(&cur_l[lnn], 1);
            if (p < SCAP) sorted_s[p] = (int)(v & 0x1FFFFu);
        }
    }
    __syncthreads();

    // ---- gather: 8 waves x 8 nodes, degree-sorted, 2-stage pipeline ----
    int nl8 = lane >> 3;             // node-slot within wave
    int c = lane & 7;                // feature octet
    int nl = perm_s[wv * 8 + nl8];   // physical local node (broadcast read)
    int n = nbase + nl;
    int d = deg_l[nl];
    int st = off_l[nl];

    int maxd = d;
    maxd = max(maxd, __shfl_xor(maxd, 8));
    maxd = max(maxd, __shfl_xor(maxd, 16));
    maxd = max(maxd, __shfl_xor(maxd, 32));

    float acc[8];
    #pragma unroll
    for (int j = 0; j < 8; j++) acc[j] = 0.0f;

    int dm1 = max(d - 1, 0);
    int sb = (d > 0) ? st : 0;

    bf16x8 rA0, rA1, rA2, rA3, rB0, rB1, rB2, rB3;
    // prologue: group A = edges 0..3
    {
        int s0 = sorted_s[sb + min(0, dm1)];
        int s1 = sorted_s[sb + min(1, dm1)];
        int s2 = sorted_s[sb + min(2, dm1)];
        int s3 = sorted_s[sb + min(3, dm1)];
        rA0 = *(const bf16x8*)&xb[(size_t)s0 * D + c * 8];
        rA1 = *(const bf16x8*)&xb[(size_t)s1 * D + c * 8];
        rA2 = *(const bf16x8*)&xb[(size_t)s2 * D + c * 8];
        rA3 = *(const bf16x8*)&xb[(size_t)s3 * D + c * 8];
    }

    for (int k = 0; k < maxd; k += 8) {
        // prefetch group B = edges k+4..k+7 (clamped, always safe)
        {
            int s0 = sorted_s[sb + min(k + 4, dm1)];
            int s1 = sorted_s[sb + min(k + 5, dm1)];
            int s2 = sorted_s[sb + min(k + 6, dm1)];
            int s3 = sorted_s[sb + min(k + 7, dm1)];
            rB0 = *(const bf16x8*)&xb[(size_t)s0 * D + c * 8];
            rB1 = *(const bf16x8*)&xb[(size_t)s1 * D + c * 8];
            rB2 = *(const bf16x8*)&xb[(size_t)s2 * D + c * 8];
            rB3 = *(const bf16x8*)&xb[(size_t)s3 * D + c * 8];
        }
        // FMA group A (edges k..k+3)
        {
            float m0 = (k + 0 < d) ? 1.0f : 0.0f;
            float m1 = (k + 1 < d) ? 1.0f : 0.0f;
            float m2 = (k + 2 < d) ? 1.0f : 0.0f;
            float m3 = (k + 3 < d) ? 1.0f : 0.0f;
            #pragma unroll
            for (int j = 0; j < 8; j++) acc[j] = fmaf(m0, bf2f((u16)rA0[j]), acc[j]);
            #pragma unroll
            for (int j = 0; j < 8; j++) acc[j] = fmaf(m1, bf2f((u16)rA1[j]), acc[j]);
            #pragma unroll
            for (int j = 0; j < 8; j++) acc[j] = fmaf(m2, bf2f((u16)rA2[j]), acc[j]);
            #pragma unroll
            for (int j = 0; j < 8; j++) acc[j] = fmaf(m3, bf2f((u16)rA3[j]), acc[j]);
        }
        // prefetch next group A = edges k+8..k+11 (uniform branch)
        if (k + 8 < maxd) {
            int s0 = sorted_s[sb + min(k + 8,  dm1)];
            int s1 = sorted_s[sb + min(k + 9,  dm1)];
            int s2 = sorted_s[sb + min(k + 10, dm1)];
            int s3 = sorted_s[sb + min(k + 11, dm1)];
            rA0 = *(const bf16x8*)&xb[(size_t)s0 * D + c * 8];
            rA1 = *(const bf16x8*)&xb[(size_t)s1 * D + c * 8];
            rA2 = *(const bf16x8*)&xb[(size_t)s2 * D + c * 8];
            rA3 = *(const bf16x8*)&xb[(size_t)s3 * D + c * 8];
        }
        // FMA group B (edges k+4..k+7), skipped entirely past maxd
        if (k + 4 < maxd) {
            float m0 = (k + 4 < d) ? 1.0f : 0.0f;
            float m1 = (k + 5 < d) ? 1.0f : 0.0f;
            float m2 = (k + 6 < d) ? 1.0f : 0.0f;
            float m3 = (k + 7 < d) ? 1.0f : 0.0f;
            #pragma unroll
            for (int j = 0; j < 8; j++) acc[j] = fmaf(m0, bf2f((u16)rB0[j]), acc[j]);
            #pragma unroll
            for (int j = 0; j < 8; j++) acc[j] = fmaf(m1, bf2f((u16)rB1[j]), acc[j]);
            #pragma unroll
            for (int j = 0; j < 8; j++) acc[j] = fmaf(m2, bf2f((u16)rB2[j]), acc[j]);
            #pragma unroll
            for (int j = 0; j < 8; j++) acc[j] = fmaf(m3, bf2f((u16)rB3[j]), acc[j]);
        }
    }

    float inv = (d > 0) ? (1.0f / (float)d) : 0.0f;
    bf16x8 p;
    #pragma unroll
    for (int j = 0; j < 8; j++) p[j] = (short)f2bf(acc[j] * inv);
    *(bf16x8*)&As[nl * STR + c * 8] = p;
    bf16x8 xr = {0, 0, 0, 0, 0, 0, 0, 0};
    if (n < N_NODES) xr = *(const bf16x8*)&xb[(size_t)n * D + c * 8];
    *(bf16x8*)&As[nl * STR + 64 + c * 8] = xr;
    __syncthreads();

    // ---- MFMA epilogue (C/D col=lane&15, row=quad*4+reg; m89/m91) ----
    int mtile = wv >> 1;             // 0..3 -> 16-row tile of 64
    int nt0 = (wv & 1) * 2;          // col tiles {0,1} or {2,3}
    int lrow = lane & 15;
    int quad = lane >> 4;

    const u16* Ab  = &As[(mtile * 16 + lrow) * STR + quad * 8];
    const u16* Bb0 = &Bs[((nt0 + 0) * 16 + lrow) * STR + quad * 8];
    const u16* Bb1 = &Bs[((nt0 + 1) * 16 + lrow) * STR + quad * 8];

    float bias0 = bl[(nt0 + 0) * 16 + lrow];
    float bias1 = bl[(nt0 + 1) * 16 + lrow];
    f32x4 acc0 = {bias0, bias0, bias0, bias0};
    f32x4 acc1 = {bias1, bias1, bias1, bias1};

    #pragma unroll
    for (int kk = 0; kk < 4; kk++) {
        bf16x8 af = *(const bf16x8*)&Ab[kk * 32];
        bf16x8 b0 = *(const bf16x8*)&Bb0[kk * 32];
        bf16x8 b1 = *(const bf16x8*)&Bb1[kk * 32];
        acc0 = __builtin_amdgcn_mfma_f32_16x16x32_bf16(af, b0, acc0, 0, 0, 0);
        acc1 = __builtin_amdgcn_mfma_f32_16x16x32_bf16(af, b1, acc1, 0, 0, 0);
    }

    int node = nbase + mtile * 16 + quad * 4;
    #pragma unroll
    for (int r = 0; r < 4; r++) {
        if (node + r < N_NODES) {
            out[(size_t)(node + r) * D + (nt0 + 0) * 16 + lrow] = fmaxf(acc0[r], 0.0f);
            out[(size_t)(node + r) * D + (nt0 + 1) * 16 + lrow] = fmaxf(acc1[r], 0.0f);
        }
    }
}

extern "C" void kernel_launch(void* const* d_in, const int* in_sizes, int n_in,
                              void* d_out, int out_size, void* d_ws, size_t ws_size,
                              hipStream_t stream) {
    const float* x  = (const float*)d_in[0];
    const int*   ei = (const int*)d_in[1];
    const float* Wl = (const float*)d_in[2];
    const float* bl = (const float*)d_in[3];
    const float* Wr = (const float*)d_in[4];
    float* out = (float*)d_out;

    // ws: cur2[NFINE*CSTR ints = 50 KB] | pairs2[NFINE*CAP2 u32 = 4.8 MB] | xb[12.8 MB]
    char* p = (char*)d_ws;
    int* cur2   = (int*)p;                        p += (size_t)NFINE * CSTR * sizeof(int);
    u32* pairs2 = (u32*)p;                        p += (size_t)NFINE * CAP2 * sizeof(u32);
    u16* xb     = (u16*)p;

    hipMemsetAsync(cur2, 0, (size_t)NFINE * CSTR * sizeof(int), stream);
    conv_build_kernel<<<FUSED_BLOCKS, 1024, 0, stream>>>(x, xb, ei, cur2, pairs2);
    cons5_kernel<<<CONS_BLOCKS, 512, 0, stream>>>(xb, Wl, bl, Wr, cur2, pairs2, out);
}

// Round 4
// 142.783 us; speedup vs baseline: 1.1319x; 1.1319x over previous
//
#include <hip/hip_runtime.h>

#define N_NODES 100000
#define N_EDGES 1000000
#define D 64

#define NFINE 782             // fine bin = dst >> 7 (128 nodes each)
#define CAP2 1536             // per-bin cap: mean 1280 + ~7 sigma
#define CHUNK 2048            // edges per build block (halved: 1 block/CU was the critical path)
#define EDGE_BLOCKS 489       // ceil(1e6 / 2048)
#define CONV_BLOCKS 6250      // N*D/4/256 exact
#define CONS_BLOCKS 3128      // 782 bins x 4 quarters, 32 nodes / 256-thr block
#define STR 132               // As/Bs row stride in u16
#define SCAP 512              // sorted_s slots per 32-node quarter (mean 320, >10 sigma)

typedef unsigned short u16;
typedef unsigned int u32;
using bf16x8 = __attribute__((ext_vector_type(8))) short;
using f32x4  = __attribute__((ext_vector_type(4))) float;

__device__ __forceinline__ u16 f2bf(float f) {   // RNE float->bf16
    u32 u = __float_as_uint(f);
    return (u16)((u + 0x7FFF + ((u >> 16) & 1)) >> 16);
}
__device__ __forceinline__ float bf2f(u16 v) {
    return __uint_as_float(((u32)v) << 16);
}

// ===========================================================================
// conv_zero: blocks [0,6250): x fp32 -> xb bf16 (1 float4/thread, full BW,
// tiny LDS so no occupancy throttle — un-fused from build after R3 showed
// the fused kernel's 37KB static LDS throttled conv streaming).
// Block 6250: zero cur2.
// ===========================================================================
__global__ __launch_bounds__(256) void conv_zero_kernel(
    const float* __restrict__ x, u16* __restrict__ xb,
    int* __restrict__ cur2) {
    if (blockIdx.x == CONV_BLOCKS) {
        for (int j = threadIdx.x; j < NFINE; j += 256) cur2[j] = 0;
        return;
    }
    int i = blockIdx.x * 256 + threadIdx.x;
    float4 v = ((const float4*)x)[i];
    ((ushort4*)xb)[i] = make_ushort4(f2bf(v.x), f2bf(v.y), f2bf(v.z), f2bf(v.w));
}

// ===========================================================================
// build4: one-pass LDS counting sort of edges into 782 fine 128-node
// dst-bins. vs R2 build3: CHUNK 4096->2048 (489 blocks): with 245 blocks
// there was exactly 1 block/CU, so kernel duration == one block's serial
// pipeline; halving the chunk halves the critical path and gives ~2
// resident blocks/CU to overlap hist-atomic / scan / scatter phases
// (LDS 24.7 KB). Packed pair = src(17b) | dst_local7 << 17.
// ===========================================================================
__global__ __launch_bounds__(1024) void build4_kernel(
    const int* __restrict__ ei, int* __restrict__ cur2,
    u32* __restrict__ pairs2) {
    __shared__ u32 sorted[CHUNK];    //  8 KB
    __shared__ u16 binof[CHUNK];     //  4 KB
    __shared__ int hist[NFINE];
    __shared__ int off_l[NFINE];
    __shared__ int cur_l[NFINE];
    __shared__ int base_g[NFINE];
    __shared__ int wsum[16];

    int b = blockIdx.x;
    int t = threadIdx.x;
    int ln = t & 63;
    int wv = t >> 6;

    // int64/int32 detect: indices < 2^17 -> int64 odd u32 words all zero
    const u32* uu = (const u32*)ei;
    int f = 1;
    #pragma unroll
    for (int i = 1; i < 16; i += 2)
        if (uu[i] != 0u) f = 0;

    if (t < NFINE) hist[t] = 0;
    __syncthreads();

    int e0 = b * CHUNK;
    int e1 = min(e0 + CHUNK, N_EDGES);
    int ne = e1 - e0;

    // load edges to registers (coalesced uint2 for int64 path) + histogram
    const uint2* e64 = (const uint2*)ei;
    int srcv[2], dstv[2];
    #pragma unroll
    for (int i = 0; i < 2; i++) {
        int ee = e0 + t + i * 1024;
        bool ok = ee < e1;
        if (f) {
            uint2 sv = ok ? e64[ee] : make_uint2(0u, 0u);
            uint2 dv = ok ? e64[N_EDGES + ee] : make_uint2(0u, 0u);
            srcv[i] = (int)sv.x;
            dstv[i] = ok ? (int)dv.x : -1;
        } else {
            srcv[i] = ok ? ei[ee] : 0;
            dstv[i] = ok ? ei[N_EDGES + ee] : -1;
        }
    }
    #pragma unroll
    for (int i = 0; i < 2; i++)
        if (dstv[i] >= 0) atomicAdd(&hist[dstv[i] >> 7], 1);
    __syncthreads();

    // two-level wave scan over 782 bins
    int h = (t < NFINE) ? hist[t] : 0;
    int inc = h;
    #pragma unroll
    for (int o = 1; o < 64; o <<= 1) {
        int v = __shfl_up(inc, o);
        if (ln >= o) inc += v;
    }
    if (ln == 63) wsum[wv] = inc;
    __syncthreads();
    if (t < 16) {
        int w = wsum[t];
        int winc = w;
        #pragma unroll
        for (int o = 1; o < 16; o <<= 1) {
            int v = __shfl_up(winc, o);
            if (t >= o) winc += v;
        }
        wsum[t] = winc - w;          // exclusive wave offset
    }
    __syncthreads();
    if (t < NFINE) {
        int ex = inc - h + wsum[wv]; // exclusive prefix
        off_l[t] = ex;
        cur_l[t] = ex;
        base_g[t] = h ? atomicAdd(&cur2[t], h) : 0;
    }
    __syncthreads();

    // placement: counting-sort into LDS
    #pragma unroll
    for (int i = 0; i < 2; i++) {
        if (dstv[i] >= 0) {
            int fine = dstv[i] >> 7;
            int slot = atomicAdd(&cur_l[fine], 1);
            sorted[slot] = (u32)srcv[i] | ((u32)(dstv[i] & 127) << 17);
            binof[slot] = (u16)fine;
        }
    }
    __syncthreads();

    // linear coalesced flush
    for (int i = t; i < ne; i += 1024) {
        int fine = binof[i];
        int pos = base_g[fine] + (i - off_l[fine]);
        if (pos < CAP2)
            pairs2[(size_t)fine * CAP2 + pos] = sorted[i];
    }
}

// ===========================================================================
// cons6: grid 3128, block 256 (4 waves), 32 nodes per block.
// bin = bid>>2 (128-node pairs2 bin), quarter = bid&3. vs R2 cons4:
//   - 256-thr/32-node blocks: LDS 27.3 KB -> 5 blocks/CU x 4 waves =
//     20 waves/CU (was 4x8 with convoyed barriers), ~12 sequential
//     blocks/CU -> many independent contexts to overlap sort/gather/MFMA
//     phases. Cost: bin pairs filtered x4 (coalesced L2 stream, cheap).
//   - gather loop is R2's proven unroll-4 VERBATIM (no added register
//     pressure; R3's 8-buffer pipeline + degree sort spilled to scratch:
//     WRITE_SIZE 25->92 MB. Verification signal this round: WRITE=25MB).
// Quarter test uses full-width compare (v>>22)==quarter so the
// 0xFFFFFFFF sentinel can never match. MFMA epilogue: mtile=wv>>1 in
// {0,1}, nt0=(wv&1)*2 (C/D col=lane&15, row=quad*4+reg; m89/m91).
// ===========================================================================
__global__ __launch_bounds__(256) void cons6_kernel(
    const u16* __restrict__ xb, const float* __restrict__ Wl,
    const float* __restrict__ bl, const float* __restrict__ Wr,
    const int* __restrict__ cur2, const u32* __restrict__ pairs2,
    float* __restrict__ out) {
    __shared__ u16 Bs[64 * STR];     // 16896 B
    __shared__ u16 As[32 * STR];     //  8448 B
    __shared__ int sorted_s[SCAP];   //  2048 B
    __shared__ int deg_l[32];
    __shared__ int off_l[32];
    __shared__ int cur_l[32];

    int tid = threadIdx.x;
    int bin = blockIdx.x >> 2;
    int quarter = blockIdx.x & 3;
    int nbase = bin * 128 + quarter * 32;
    if (nbase >= N_NODES) return;    // phantom quarters of last bin

    int lane = tid & 63;
    int wv = tid >> 6;

    // ---- issue pair loads first (long-latency, hide under staging) ----
    int cnt = min(cur2[bin], CAP2);
    const u32* pb = &pairs2[(size_t)bin * CAP2];
    u32 ve[6];                       // CAP2/256 == 6
    #pragma unroll
    for (int i = 0; i < 6; i++) {
        int e = tid + i * 256;
        ve[i] = (e < cnt) ? pb[e] : 0xFFFFFFFFu;   // sentinel fails quarter test
    }

    if (tid < 32) { deg_l[tid] = 0; cur_l[tid] = 0; }
    if (tid == 0) sorted_s[0] = 0;   // safe slot for d==0 lanes

    // Stage Bs: row o = [Wl[o][0:64] | Wr[o][0:64]] bf16, stride STR
    {
        int row = tid >> 2;
        int seg = tid & 3;
        const float4* wlf = (const float4*)Wl;
        const float4* wrf = (const float4*)Wr;
        #pragma unroll
        for (int j = 0; j < 4; j++) {
            float4 a = wlf[row * 16 + seg * 4 + j];
            float4 bq = wrf[row * 16 + seg * 4 + j];
            *(ushort4*)&Bs[row * STR + seg * 16 + j * 4] =
                make_ushort4(f2bf(a.x), f2bf(a.y), f2bf(a.z), f2bf(a.w));
            *(ushort4*)&Bs[row * STR + 64 + seg * 16 + j * 4] =
                make_ushort4(f2bf(bq.x), f2bf(bq.y), f2bf(bq.z), f2bf(bq.w));
        }
    }
    __syncthreads();

    // ---- histogram over this quarter's 32 local nodes ----
    #pragma unroll
    for (int i = 0; i < 6; i++) {
        u32 v = ve[i];
        if ((int)(v >> 22) == quarter) atomicAdd(&deg_l[(v >> 17) & 31], 1);
    }
    __syncthreads();

    // ---- exclusive scan of 32 degrees (lanes 0..31 of wave 0) ----
    if (tid < 32) {
        int dd = deg_l[tid];
        int inc = dd;
        #pragma unroll
        for (int o = 1; o < 32; o <<= 1) {
            int v = __shfl_up(inc, o);
            if (tid >= o) inc += v;
        }
        off_l[tid] = inc - dd;
    }
    __syncthreads();

    // ---- counting-sort placement ----
    #pragma unroll
    for (int i = 0; i < 6; i++) {
        u32 v = ve[i];
        if ((int)(v >> 22) == quarter) {
            int lnn = (v >> 17) & 31;
            int p = off_l[lnn] + atomicAdd(&cur_l[lnn], 1);
            if (p < SCAP) sorted_s[p] = (int)(v & 0x1FFFFu);
        }
    }
    __syncthreads();

    // ---- gather: 4 waves x 8 nodes, unroll 4 (4 loads in flight) ----
    int nl8 = lane >> 3;             // node within wave
    int c = lane & 7;                // feature octet
    int nl = wv * 8 + nl8;           // local node 0..31
    int n = nbase + nl;
    int d = deg_l[nl];
    int st = off_l[nl];

    int maxd = d;
    maxd = max(maxd, __shfl_xor(maxd, 8));
    maxd = max(maxd, __shfl_xor(maxd, 16));
    maxd = max(maxd, __shfl_xor(maxd, 32));

    float acc[8];
    #pragma unroll
    for (int j = 0; j < 8; j++) acc[j] = 0.0f;

    int dm1 = (d > 0) ? (d - 1) : 0;
    int sb = (d > 0) ? st : 0;
    for (int k = 0; k < maxd; k += 4) {
        int i0 = sb + min(k + 0, dm1);
        int i1 = sb + min(k + 1, dm1);
        int i2 = sb + min(k + 2, dm1);
        int i3 = sb + min(k + 3, dm1);
        int s0 = sorted_s[i0];
        int s1 = sorted_s[i1];
        int s2 = sorted_s[i2];
        int s3 = sorted_s[i3];
        bf16x8 r0 = *(const bf16x8*)&xb[(size_t)s0 * D + c * 8];
        bf16x8 r1 = *(const bf16x8*)&xb[(size_t)s1 * D + c * 8];
        bf16x8 r2 = *(const bf16x8*)&xb[(size_t)s2 * D + c * 8];
        bf16x8 r3 = *(const bf16x8*)&xb[(size_t)s3 * D + c * 8];
        float m0 = (k + 0 < d) ? 1.0f : 0.0f;
        float m1 = (k + 1 < d) ? 1.0f : 0.0f;
        float m2 = (k + 2 < d) ? 1.0f : 0.0f;
        float m3 = (k + 3 < d) ? 1.0f : 0.0f;
        #pragma unroll
        for (int j = 0; j < 8; j++)
            acc[j] = fmaf(m0, bf2f((u16)r0[j]), acc[j]);
        #pragma unroll
        for (int j = 0; j < 8; j++)
            acc[j] = fmaf(m1, bf2f((u16)r1[j]), acc[j]);
        #pragma unroll
        for (int j = 0; j < 8; j++)
            acc[j] = fmaf(m2, bf2f((u16)r2[j]), acc[j]);
        #pragma unroll
        for (int j = 0; j < 8; j++)
            acc[j] = fmaf(m3, bf2f((u16)r3[j]), acc[j]);
    }

    float inv = (d > 0) ? (1.0f / (float)d) : 0.0f;
    bf16x8 p;
    #pragma unroll
    for (int j = 0; j < 8; j++) p[j] = (short)f2bf(acc[j] * inv);
    *(bf16x8*)&As[nl * STR + c * 8] = p;
    bf16x8 xr = {0, 0, 0, 0, 0, 0, 0, 0};
    if (n < N_NODES) xr = *(const bf16x8*)&xb[(size_t)n * D + c * 8];
    *(bf16x8*)&As[nl * STR + 64 + c * 8] = xr;
    __syncthreads();

    // ---- MFMA epilogue (C/D col=lane&15, row=quad*4+reg; m89/m91) ----
    int mtile = wv >> 1;             // 0..1 -> 16-row tile of 32
    int nt0 = (wv & 1) * 2;          // col tiles {0,1} or {2,3}
    int lrow = lane & 15;
    int quad = lane >> 4;

    const u16* Ab  = &As[(mtile * 16 + lrow) * STR + quad * 8];
    const u16* Bb0 = &Bs[((nt0 + 0) * 16 + lrow) * STR + quad * 8];
    const u16* Bb1 = &Bs[((nt0 + 1) * 16 + lrow) * STR + quad * 8];

    float bias0 = bl[(nt0 + 0) * 16 + lrow];
    float bias1 = bl[(nt0 + 1) * 16 + lrow];
    f32x4 acc0 = {bias0, bias0, bias0, bias0};
    f32x4 acc1 = {bias1, bias1, bias1, bias1};

    #pragma unroll
    for (int kk = 0; kk < 4; kk++) {
        bf16x8 af = *(const bf16x8*)&Ab[kk * 32];
        bf16x8 b0 = *(const bf16x8*)&Bb0[kk * 32];
        bf16x8 b1 = *(const bf16x8*)&Bb1[kk * 32];
        acc0 = __builtin_amdgcn_mfma_f32_16x16x32_bf16(af, b0, acc0, 0, 0, 0);
        acc1 = __builtin_amdgcn_mfma_f32_16x16x32_bf16(af, b1, acc1, 0, 0, 0);
    }

    int node = nbase + mtile * 16 + quad * 4;
    #pragma unroll
    for (int r = 0; r < 4; r++) {
        if (node + r < N_NODES) {
            out[(size_t)(node + r) * D + (nt0 + 0) * 16 + lrow] = fmaxf(acc0[r], 0.0f);
            out[(size_t)(node + r) * D + (nt0 + 1) * 16 + lrow] = fmaxf(acc1[r], 0.0f);
        }
    }
}

extern "C" void kernel_launch(void* const* d_in, const int* in_sizes, int n_in,
                              void* d_out, int out_size, void* d_ws, size_t ws_size,
                              hipStream_t stream) {
    const float* x  = (const float*)d_in[0];
    const int*   ei = (const int*)d_in[1];
    const float* Wl = (const float*)d_in[2];
    const float* bl = (const float*)d_in[3];
    const float* Wr = (const float*)d_in[4];
    float* out = (float*)d_out;

    // ws: cur2[1024 ints] | pairs2[NFINE*CAP2 u32 = 4.8 MB] | xb[12.8 MB]
    char* p = (char*)d_ws;
    int* cur2   = (int*)p;                        p += 1024 * sizeof(int);
    u32* pairs2 = (u32*)p;                        p += (size_t)NFINE * CAP2 * sizeof(u32);
    u16* xb     = (u16*)p;

    conv_zero_kernel<<<CONV_BLOCKS + 1, 256, 0, stream>>>(x, xb, cur2);
    build4_kernel<<<EDGE_BLOCKS, 1024, 0, stream>>>(ei, cur2, pairs2);
    cons6_kernel<<<CONS_BLOCKS, 256, 0, stream>>>(xb, Wl, bl, Wr, cur2, pairs2, out);
}

// Round 5
// 130.776 us; speedup vs baseline: 1.2358x; 1.0918x over previous
//
#include <hip/hip_runtime.h>

#define N_NODES 100000
#define N_EDGES 1000000
#define D 64

#define NFINE 782             // fine bin = dst >> 7 (128 nodes each)
#define CAP2 1536             // per-bin cap: mean 1280 + ~7 sigma
#define CHUNK 4096            // edges per build block (R2-measured best; 2048 lost ~5us)
#define EDGE_BLOCKS 245       // ceil(1e6 / 4096)
#define CONV_BLOCKS 6250      // N*D/4/256 exact
#define CONS_BLOCKS 3128      // 782 bins x 4 quarters, 32 nodes / 256-thr block
#define STR 132               // As row stride in u16: 2-way-free bank pattern
#define SCAP 512              // sorted_s slots per 32-node quarter (mean 320, >10 sigma)

typedef unsigned short u16;
typedef unsigned int u32;
using bf16x8 = __attribute__((ext_vector_type(8))) short;
using f32x4  = __attribute__((ext_vector_type(4))) float;

__device__ __forceinline__ u16 f2bf(float f) {   // RNE float->bf16
    u32 u = __float_as_uint(f);
    return (u16)((u + 0x7FFF + ((u >> 16) & 1)) >> 16);
}
__device__ __forceinline__ float bf2f(u16 v) {
    return __uint_as_float(((u32)v) << 16);
}

// ===========================================================================
// conv_zero: blocks [0,6250): x fp32 -> xb bf16 (1 float4/thread, full BW).
// Block 6250: zero cur2. Block 6251: pre-convert weights into Wb bf16
// [64 rows o][128 k] row-major ([Wl row | Wr row]) — done ONCE here so the
// 3128 cons blocks load B-fragments directly into registers (no Bs LDS).
// ===========================================================================
__global__ __launch_bounds__(256) void conv_zero_kernel(
    const float* __restrict__ x, u16* __restrict__ xb,
    int* __restrict__ cur2,
    const float* __restrict__ Wl, const float* __restrict__ Wr,
    u16* __restrict__ Wb) {
    if (blockIdx.x == CONV_BLOCKS) {
        for (int j = threadIdx.x; j < NFINE; j += 256) cur2[j] = 0;
        return;
    }
    if (blockIdx.x == CONV_BLOCKS + 1) {
        // 64 rows x 128 cols; thread t: row o = t>>2, k-range seg = (t&3)*32
        int o = threadIdx.x >> 2;
        int k0 = (threadIdx.x & 3) * 32;
        const float4* wlf = (const float4*)Wl;
        const float4* wrf = (const float4*)Wr;
        #pragma unroll
        for (int j = 0; j < 8; j++) {
            int k = k0 + j * 4;
            float4 v = (k < 64) ? wlf[(o * 64 + k) >> 2]
                                : wrf[(o * 64 + k - 64) >> 2];
            *(ushort4*)&Wb[o * 128 + k] =
                make_ushort4(f2bf(v.x), f2bf(v.y), f2bf(v.z), f2bf(v.w));
        }
        return;
    }
    int i = blockIdx.x * 256 + threadIdx.x;
    float4 v = ((const float4*)x)[i];
    ((ushort4*)xb)[i] = make_ushort4(f2bf(v.x), f2bf(v.y), f2bf(v.z), f2bf(v.w));
}

// ===========================================================================
// build3: one-pass LDS counting sort of edges into 782 fine 128-node
// dst-bins. R2-measured best config (CHUNK 4096, 245 blocks; R4's 2048
// regressed ~5us: doubled per-block scan + reservation-atomic cost).
// Packed pair = src(17b) | dst_local7 << 17.
// ===========================================================================
__global__ __launch_bounds__(1024) void build3_kernel(
    const int* __restrict__ ei, int* __restrict__ cur2,
    u32* __restrict__ pairs2) {
    __shared__ u32 sorted[CHUNK];    // 16 KB
    __shared__ u16 binof[CHUNK];     //  8 KB
    __shared__ int hist[NFINE];
    __shared__ int off_l[NFINE];
    __shared__ int cur_l[NFINE];
    __shared__ int base_g[NFINE];
    __shared__ int wsum[16];

    int b = blockIdx.x;
    int t = threadIdx.x;
    int ln = t & 63;
    int wv = t >> 6;

    // int64/int32 detect: indices < 2^17 -> int64 odd u32 words all zero
    const u32* uu = (const u32*)ei;
    int f = 1;
    #pragma unroll
    for (int i = 1; i < 16; i += 2)
        if (uu[i] != 0u) f = 0;

    if (t < NFINE) hist[t] = 0;
    __syncthreads();

    int e0 = b * CHUNK;
    int e1 = min(e0 + CHUNK, N_EDGES);
    int ne = e1 - e0;

    // load edges to registers (coalesced uint2 for int64 path) + histogram
    const uint2* e64 = (const uint2*)ei;
    int srcv[4], dstv[4];
    #pragma unroll
    for (int i = 0; i < 4; i++) {
        int ee = e0 + t + i * 1024;
        bool ok = ee < e1;
        if (f) {
            uint2 sv = ok ? e64[ee] : make_uint2(0u, 0u);
            uint2 dv = ok ? e64[N_EDGES + ee] : make_uint2(0u, 0u);
            srcv[i] = (int)sv.x;
            dstv[i] = ok ? (int)dv.x : -1;
        } else {
            srcv[i] = ok ? ei[ee] : 0;
            dstv[i] = ok ? ei[N_EDGES + ee] : -1;
        }
    }
    #pragma unroll
    for (int i = 0; i < 4; i++)
        if (dstv[i] >= 0) atomicAdd(&hist[dstv[i] >> 7], 1);
    __syncthreads();

    // two-level wave scan over 782 bins
    int h = (t < NFINE) ? hist[t] : 0;
    int inc = h;
    #pragma unroll
    for (int o = 1; o < 64; o <<= 1) {
        int v = __shfl_up(inc, o);
        if (ln >= o) inc += v;
    }
    if (ln == 63) wsum[wv] = inc;
    __syncthreads();
    if (t < 16) {
        int w = wsum[t];
        int winc = w;
        #pragma unroll
        for (int o = 1; o < 16; o <<= 1) {
            int v = __shfl_up(winc, o);
            if (t >= o) winc += v;
        }
        wsum[t] = winc - w;          // exclusive wave offset
    }
    __syncthreads();
    if (t < NFINE) {
        int ex = inc - h + wsum[wv]; // exclusive prefix
        off_l[t] = ex;
        cur_l[t] = ex;
        base_g[t] = h ? atomicAdd(&cur2[t], h) : 0;
    }
    __syncthreads();

    // placement: counting-sort into LDS
    #pragma unroll
    for (int i = 0; i < 4; i++) {
        if (dstv[i] >= 0) {
            int fine = dstv[i] >> 7;
            int slot = atomicAdd(&cur_l[fine], 1);
            sorted[slot] = (u32)srcv[i] | ((u32)(dstv[i] & 127) << 17);
            binof[slot] = (u16)fine;
        }
    }
    __syncthreads();

    // linear coalesced flush
    for (int i = t; i < ne; i += 1024) {
        int fine = binof[i];
        int pos = base_g[fine] + (i - off_l[fine]);
        if (pos < CAP2)
            pairs2[(size_t)fine * CAP2 + pos] = sorted[i];
    }
}

// ===========================================================================
// cons7: grid 3128, block 256 (4 waves), 32 nodes per block.
// vs R4 cons6 (44.3us, VALUBusy 23% = latency-bound, per-wave duty ~5%):
//   - NO Bs LDS: weights pre-converted to Wb bf16 [64][128] by conv_zero;
//     each wave loads its 8 B-fragments (8 dwordx4, L2-hot) into registers
//     AFTER the gather (buffers dead there). LDS 28.2 -> 10.9 KB ->
//     blocks/CU 5 -> 7-8 (~28-32 waves/CU vs 20).
//   - gather FLAT unroll-8: 8 independent 16B loads in flight per lane
//     (2x memory parallelism). Flat = no cross-iter pipelining/degree-sort
//     (R3's spill cause). Spill tripwire: WRITE_SIZE must stay 25 MB.
// MFMA epilogue layout unchanged (C/D col=lane&15, row=quad*4+reg; m89/m91).
// ===========================================================================
__global__ __launch_bounds__(256) void cons7_kernel(
    const u16* __restrict__ xb, const u16* __restrict__ Wb,
    const float* __restrict__ bl,
    const int* __restrict__ cur2, const u32* __restrict__ pairs2,
    float* __restrict__ out) {
    __shared__ u16 As[32 * STR];     //  8448 B
    __shared__ int sorted_s[SCAP];   //  2048 B
    __shared__ int deg_l[32];
    __shared__ int off_l[32];
    __shared__ int cur_l[32];

    int tid = threadIdx.x;
    int bin = blockIdx.x >> 2;
    int quarter = blockIdx.x & 3;
    int nbase = bin * 128 + quarter * 32;
    if (nbase >= N_NODES) return;    // phantom quarters of last bin

    int lane = tid & 63;
    int wv = tid >> 6;

    // ---- issue pair loads first (long-latency, hide under init) ----
    int cnt = min(cur2[bin], CAP2);
    const u32* pb = &pairs2[(size_t)bin * CAP2];
    u32 ve[6];                       // CAP2/256 == 6
    #pragma unroll
    for (int i = 0; i < 6; i++) {
        int e = tid + i * 256;
        ve[i] = (e < cnt) ? pb[e] : 0xFFFFFFFFu;   // sentinel fails quarter test
    }

    if (tid < 32) { deg_l[tid] = 0; cur_l[tid] = 0; }
    if (tid == 0) sorted_s[0] = 0;   // safe slot for d==0 lanes
    __syncthreads();

    // ---- histogram over this quarter's 32 local nodes ----
    #pragma unroll
    for (int i = 0; i < 6; i++) {
        u32 v = ve[i];
        if ((int)(v >> 22) == quarter) atomicAdd(&deg_l[(v >> 17) & 31], 1);
    }
    __syncthreads();

    // ---- exclusive scan of 32 degrees (lanes 0..31 of wave 0) ----
    if (tid < 32) {
        int dd = deg_l[tid];
        int inc = dd;
        #pragma unroll
        for (int o = 1; o < 32; o <<= 1) {
            int v = __shfl_up(inc, o);
            if (tid >= o) inc += v;
        }
        off_l[tid] = inc - dd;
    }
    __syncthreads();

    // ---- counting-sort placement ----
    #pragma unroll
    for (int i = 0; i < 6; i++) {
        u32 v = ve[i];
        if ((int)(v >> 22) == quarter) {
            int lnn = (v >> 17) & 31;
            int p = off_l[lnn] + atomicAdd(&cur_l[lnn], 1);
            if (p < SCAP) sorted_s[p] = (int)(v & 0x1FFFFu);
        }
    }
    __syncthreads();

    // ---- gather: 4 waves x 8 nodes, FLAT unroll-8 (8 loads in flight) ----
    int nl8 = lane >> 3;             // node within wave
    int c = lane & 7;                // feature octet
    int nl = wv * 8 + nl8;           // local node 0..31
    int n = nbase + nl;
    int d = deg_l[nl];
    int st = off_l[nl];

    int maxd = d;
    maxd = max(maxd, __shfl_xor(maxd, 8));
    maxd = max(maxd, __shfl_xor(maxd, 16));
    maxd = max(maxd, __shfl_xor(maxd, 32));

    float acc[8];
    #pragma unroll
    for (int j = 0; j < 8; j++) acc[j] = 0.0f;

    int dm1 = (d > 0) ? (d - 1) : 0;
    int sb = (d > 0) ? st : 0;
    for (int k = 0; k < maxd; k += 8) {
        int ix[8];
        #pragma unroll
        for (int u = 0; u < 8; u++) ix[u] = sb + min(k + u, dm1);
        int s0 = sorted_s[ix[0]];
        int s1 = sorted_s[ix[1]];
        int s2 = sorted_s[ix[2]];
        int s3 = sorted_s[ix[3]];
        int s4 = sorted_s[ix[4]];
        int s5 = sorted_s[ix[5]];
        int s6 = sorted_s[ix[6]];
        int s7 = sorted_s[ix[7]];
        bf16x8 r0 = *(const bf16x8*)&xb[(size_t)s0 * D + c * 8];
        bf16x8 r1 = *(const bf16x8*)&xb[(size_t)s1 * D + c * 8];
        bf16x8 r2 = *(const bf16x8*)&xb[(size_t)s2 * D + c * 8];
        bf16x8 r3 = *(const bf16x8*)&xb[(size_t)s3 * D + c * 8];
        bf16x8 r4 = *(const bf16x8*)&xb[(size_t)s4 * D + c * 8];
        bf16x8 r5 = *(const bf16x8*)&xb[(size_t)s5 * D + c * 8];
        bf16x8 r6 = *(const bf16x8*)&xb[(size_t)s6 * D + c * 8];
        bf16x8 r7 = *(const bf16x8*)&xb[(size_t)s7 * D + c * 8];
        float m0 = (k + 0 < d) ? 1.0f : 0.0f;
        float m1 = (k + 1 < d) ? 1.0f : 0.0f;
        float m2 = (k + 2 < d) ? 1.0f : 0.0f;
        float m3 = (k + 3 < d) ? 1.0f : 0.0f;
        float m4 = (k + 4 < d) ? 1.0f : 0.0f;
        float m5 = (k + 5 < d) ? 1.0f : 0.0f;
        float m6 = (k + 6 < d) ? 1.0f : 0.0f;
        float m7 = (k + 7 < d) ? 1.0f : 0.0f;
        #pragma unroll
        for (int j = 0; j < 8; j++) acc[j] = fmaf(m0, bf2f((u16)r0[j]), acc[j]);
        #pragma unroll
        for (int j = 0; j < 8; j++) acc[j] = fmaf(m1, bf2f((u16)r1[j]), acc[j]);
        #pragma unroll
        for (int j = 0; j < 8; j++) acc[j] = fmaf(m2, bf2f((u16)r2[j]), acc[j]);
        #pragma unroll
        for (int j = 0; j < 8; j++) acc[j] = fmaf(m3, bf2f((u16)r3[j]), acc[j]);
        #pragma unroll
        for (int j = 0; j < 8; j++) acc[j] = fmaf(m4, bf2f((u16)r4[j]), acc[j]);
        #pragma unroll
        for (int j = 0; j < 8; j++) acc[j] = fmaf(m5, bf2f((u16)r5[j]), acc[j]);
        #pragma unroll
        for (int j = 0; j < 8; j++) acc[j] = fmaf(m6, bf2f((u16)r6[j]), acc[j]);
        #pragma unroll
        for (int j = 0; j < 8; j++) acc[j] = fmaf(m7, bf2f((u16)r7[j]), acc[j]);
    }

    // ---- epilogue coords (needed for B-frag addresses) ----
    int mtile = wv >> 1;             // 0..1 -> 16-row tile of 32
    int nt0 = (wv & 1) * 2;          // col tiles {0,1} or {2,3}
    int lrow = lane & 15;
    int quad = lane >> 4;

    // issue B-fragment loads from Wb (bf16 [64][128], L2-hot) — latency
    // hides under As writes + barrier; gather buffers are dead here.
    const u16* wb0 = &Wb[((nt0 + 0) * 16 + lrow) * 128 + quad * 8];
    const u16* wb1 = &Wb[((nt0 + 1) * 16 + lrow) * 128 + quad * 8];
    bf16x8 bf0_0 = *(const bf16x8*)&wb0[0 * 32];
    bf16x8 bf0_1 = *(const bf16x8*)&wb0[1 * 32];
    bf16x8 bf0_2 = *(const bf16x8*)&wb0[2 * 32];
    bf16x8 bf0_3 = *(const bf16x8*)&wb0[3 * 32];
    bf16x8 bf1_0 = *(const bf16x8*)&wb1[0 * 32];
    bf16x8 bf1_1 = *(const bf16x8*)&wb1[1 * 32];
    bf16x8 bf1_2 = *(const bf16x8*)&wb1[2 * 32];
    bf16x8 bf1_3 = *(const bf16x8*)&wb1[3 * 32];

    float inv = (d > 0) ? (1.0f / (float)d) : 0.0f;
    bf16x8 p;
    #pragma unroll
    for (int j = 0; j < 8; j++) p[j] = (short)f2bf(acc[j] * inv);
    *(bf16x8*)&As[nl * STR + c * 8] = p;
    bf16x8 xr = {0, 0, 0, 0, 0, 0, 0, 0};
    if (n < N_NODES) xr = *(const bf16x8*)&xb[(size_t)n * D + c * 8];
    *(bf16x8*)&As[nl * STR + 64 + c * 8] = xr;
    __syncthreads();

    // ---- MFMA epilogue (C/D col=lane&15, row=quad*4+reg; m89/m91) ----
    const u16* Ab = &As[(mtile * 16 + lrow) * STR + quad * 8];

    float bias0 = bl[(nt0 + 0) * 16 + lrow];
    float bias1 = bl[(nt0 + 1) * 16 + lrow];
    f32x4 acc0 = {bias0, bias0, bias0, bias0};
    f32x4 acc1 = {bias1, bias1, bias1, bias1};

    {
        bf16x8 af;
        af = *(const bf16x8*)&Ab[0 * 32];
        acc0 = __builtin_amdgcn_mfma_f32_16x16x32_bf16(af, bf0_0, acc0, 0, 0, 0);
        acc1 = __builtin_amdgcn_mfma_f32_16x16x32_bf16(af, bf1_0, acc1, 0, 0, 0);
        af = *(const bf16x8*)&Ab[1 * 32];
        acc0 = __builtin_amdgcn_mfma_f32_16x16x32_bf16(af, bf0_1, acc0, 0, 0, 0);
        acc1 = __builtin_amdgcn_mfma_f32_16x16x32_bf16(af, bf1_1, acc1, 0, 0, 0);
        af = *(const bf16x8*)&Ab[2 * 32];
        acc0 = __builtin_amdgcn_mfma_f32_16x16x32_bf16(af, bf0_2, acc0, 0, 0, 0);
        acc1 = __builtin_amdgcn_mfma_f32_16x16x32_bf16(af, bf1_2, acc1, 0, 0, 0);
        af = *(const bf16x8*)&Ab[3 * 32];
        acc0 = __builtin_amdgcn_mfma_f32_16x16x32_bf16(af, bf0_3, acc0, 0, 0, 0);
        acc1 = __builtin_amdgcn_mfma_f32_16x16x32_bf16(af, bf1_3, acc1, 0, 0, 0);
    }

    int node = nbase + mtile * 16 + quad * 4;
    #pragma unroll
    for (int r = 0; r < 4; r++) {
        if (node + r < N_NODES) {
            out[(size_t)(node + r) * D + (nt0 + 0) * 16 + lrow] = fmaxf(acc0[r], 0.0f);
            out[(size_t)(node + r) * D + (nt0 + 1) * 16 + lrow] = fmaxf(acc1[r], 0.0f);
        }
    }
}

extern "C" void kernel_launch(void* const* d_in, const int* in_sizes, int n_in,
                              void* d_out, int out_size, void* d_ws, size_t ws_size,
                              hipStream_t stream) {
    const float* x  = (const float*)d_in[0];
    const int*   ei = (const int*)d_in[1];
    const float* Wl = (const float*)d_in[2];
    const float* bl = (const float*)d_in[3];
    const float* Wr = (const float*)d_in[4];
    float* out = (float*)d_out;

    // ws: cur2[1024 ints = 4 KB] | Wb[8192 u16 = 16 KB] |
    //     pairs2[NFINE*CAP2 u32 = 4.8 MB] | xb[12.8 MB]
    char* p = (char*)d_ws;
    int* cur2   = (int*)p;                        p += 1024 * sizeof(int);
    u16* Wb     = (u16*)p;                        p += 8192 * sizeof(u16);
    u32* pairs2 = (u32*)p;                        p += (size_t)NFINE * CAP2 * sizeof(u32);
    u16* xb     = (u16*)p;

    conv_zero_kernel<<<CONV_BLOCKS + 2, 256, 0, stream>>>(x, xb, cur2, Wl, Wr, Wb);
    build3_kernel<<<EDGE_BLOCKS, 1024, 0, stream>>>(ei, cur2, pairs2);
    cons7_kernel<<<CONS_BLOCKS, 256, 0, stream>>>(xb, Wb, bl, cur2, pairs2, out);
}